// Round 6
// baseline (396.663 us; speedup 1.0000x reference)
//
#include <hip/hip_runtime.h>

// GNN, fixed shapes: B=128 graphs x N=64 nodes, D=64 features, M=8192, HL=3, OL=2.
// adjacency [8192x8192] f32 is block-diagonal (128 diagonal 64x64 symmetric 0/1
// blocks). All float tensors f32; fingerprints int32.
//
// R6: R5 structure (128 persistent blocks x 256 threads, x resident in LDS,
// fused MLP head in block 0) with cheap synchronization:
//  - grid barrier = phase-stamped arrival array arr[128] (release store own slot,
//    acquire-poll one slot per thread) -- no single-cacheline fetch_add chain.
//  - BN stats = per-block partial slots + redundant post-barrier reduce -- no
//    atomicAdd storm, no zeroed stats needed.
//  - final phase is arrival-only: blocks 1..127 stamp & retire; block 0 waits.
// Only arr (512 B) needs pre-zero/poison-tolerance; 0xAA poison is negative ints
// so polling (< phase) is safe; a 512 B memset guards the first call.
#define MT   8192
#define DD   64
#define NPG  64
#define NB   128
#define XP   68          // xsc/wT column stride (floats)
#define TP   68          // head t row stride (floats)
#define BN_EPS 1e-5f

__device__ __forceinline__ float selu_f(float x) {
  const float scale = 1.0507009873554804934f;
  const float alpha = 1.6732632423543772848f;
  return x > 0.f ? scale * x : scale * alpha * (__expf(x) - 1.f);
}

// Stamp own arrival slot with the phase number (release: prior block writes
// visible device-wide before the stamp lands).
__device__ __forceinline__ void stamp(int* arr, int b, int ph) {
  __syncthreads();   // all block threads' global writes issued & drained
  if (threadIdx.x == 0)
    __hip_atomic_store(&arr[b], ph, __ATOMIC_RELEASE, __HIP_MEMORY_SCOPE_AGENT);
}

// Wait until all 128 blocks stamped >= ph. One poller thread per slot.
__device__ __forceinline__ void wait_all(int* arr, int ph) {
  if (threadIdx.x < NB) {
    while (__hip_atomic_load(&arr[threadIdx.x], __ATOMIC_ACQUIRE,
                             __HIP_MEMORY_SCOPE_AGENT) < ph)
      __builtin_amdgcn_s_sleep(1);
  }
  __syncthreads();
}

__global__ __launch_bounds__(256) void gnn_k(
    const int* __restrict__ fpr,
    const float* __restrict__ emb,     // [NFP,64]
    const float* __restrict__ adj,     // [8192,8192]
    const float* __restrict__ Wf,      // [3,64,64]
    const float* __restrict__ bfv,     // [3,64]
    const float* __restrict__ Wo,      // [2,64,64]
    const float* __restrict__ bo,      // [2,64]
    const float* __restrict__ Wp,      // [64]
    const float* __restrict__ bp,      // [1]
    float* __restrict__ out,           // [128]
    float* __restrict__ mol,           // scratch [128,64]
    float* __restrict__ part,          // [3][128][128] per-block BN partials
    int* __restrict__ arr)             // [128] arrival slots (zeroed/poisoned)
{
  __shared__ char pool[55808];
  float* xsc = (float*)pool;                   // [0,17408): x col-major xsc[d*XP+n]
  float* wT  = (float*)(pool + 17408);         // [17408,34816): wT[k*XP+c]=W[c][k]
  float* hs  = (float*)(pool + 34816);         // [34816,51200): hs[n*64+d]
  unsigned char* aU = (unsigned char*)(pool + 51200); // [51200,55296): A bytes
  float* mus = (float*)(pool + 55296);         // 256 B
  float* rss = (float*)(pool + 55552);         // 256 B
  float* red1 = wT;                            // overlay (wT dead at that point)
  float* red2 = wT + 1024;

  const int tid = threadIdx.x, b = blockIdx.x;
  const int tr = tid >> 4, tc = tid & 15;
  const int n0 = tr * 4, c0 = tc * 4;

  // ---- stage A block (bytes), W^T(layer0), x (embed gather, col-major) ----
  for (int j = 0; j < 4; ++j) {
    int e = (tid + j * 256) * 4;
    int r = e >> 6, k = e & 63;
    float4 av = *(const float4*)(adj + (size_t)(b * NPG + r) * MT + b * NPG + k);
    uchar4 u;
    u.x = (unsigned char)av.x; u.y = (unsigned char)av.y;
    u.z = (unsigned char)av.z; u.w = (unsigned char)av.w;
    *(uchar4*)(aU + e) = u;
    float4 wv = *(const float4*)(Wf + e);          // W[r][k..k+3]
    wT[(k + 0) * XP + r] = wv.x;
    wT[(k + 1) * XP + r] = wv.y;
    wT[(k + 2) * XP + r] = wv.z;
    wT[(k + 3) * XP + r] = wv.w;
    int f = fpr[b * NPG + r];
    float4 xv = *(const float4*)(emb + (size_t)f * DD + k);
    xsc[(k + 0) * XP + r] = xv.x;
    xsc[(k + 1) * XP + r] = xv.y;
    xsc[(k + 2) * XP + r] = xv.z;
    xsc[(k + 3) * XP + r] = xv.w;
  }
  __syncthreads();

  float poolp = 0.f;

  for (int l = 0; l < 3; ++l) {
    // ---- GEMM1: h = selu(x @ W^T + b); operand reads are lane-duplicated ----
    {
      float acc[4][4] = {};
#pragma unroll 4
      for (int d = 0; d < DD; ++d) {
        float4 xv = *(const float4*)(xsc + d * XP + n0);
        float4 wv = *(const float4*)(wT + d * XP + c0);
#pragma unroll
        for (int i = 0; i < 4; ++i) {
          float xk = ((const float*)&xv)[i];
          acc[i][0] += xk * wv.x;
          acc[i][1] += xk * wv.y;
          acc[i][2] += xk * wv.z;
          acc[i][3] += xk * wv.w;
        }
      }
      float b4[4];
#pragma unroll
      for (int c = 0; c < 4; ++c) b4[c] = bfv[l * DD + c0 + c];
#pragma unroll
      for (int i = 0; i < 4; ++i) {
        float4 hv;
        hv.x = selu_f(acc[i][0] + b4[0]);
        hv.y = selu_f(acc[i][1] + b4[1]);
        hv.z = selu_f(acc[i][2] + b4[2]);
        hv.w = selu_f(acc[i][3] + b4[3]);
        *(float4*)(hs + (n0 + i) * DD + c0) = hv;
      }
    }
    __syncthreads();   // hs ready; wT dead -> red1/red2 usable

    // ---- GEMM2: y = x + A @ h (A via symmetry: aU[k*64+n] = A[n][k]) ----
    {
      float acc[4][4] = {};
#pragma unroll 4
      for (int k = 0; k < DD; ++k) {
        uchar4 a4 = *(const uchar4*)(aU + k * DD + n0);
        float4 hv = *(const float4*)(hs + k * DD + c0);
        float af[4] = { (float)a4.x, (float)a4.y, (float)a4.z, (float)a4.w };
#pragma unroll
        for (int i = 0; i < 4; ++i) {
          acc[i][0] += af[i] * hv.x;
          acc[i][1] += af[i] * hv.y;
          acc[i][2] += af[i] * hv.z;
          acc[i][3] += af[i] * hv.w;
        }
      }
#pragma unroll
      for (int c = 0; c < 4; ++c) {
        float* p = xsc + (c0 + c) * XP + n0;
        float4 xo = *(const float4*)p;
        float y0 = acc[0][c] + xo.x;
        float y1 = acc[1][c] + xo.y;
        float y2 = acc[2][c] + xo.z;
        float y3 = acc[3][c] + xo.w;
        float4 yv = { y0, y1, y2, y3 };
        *(float4*)p = yv;
        red1[tr * DD + c0 + c] = y0 + y1 + y2 + y3;
        red2[tr * DD + c0 + c] = y0 * y0 + y1 * y1 + y2 * y2 + y3 * y3;
      }
    }
    __syncthreads();
    // ---- per-block BN partials -> own slot (no atomics, no zero-init) ----
    if (tid < DD) {
      float t1 = 0.f, t2 = 0.f;
#pragma unroll
      for (int q = 0; q < 16; ++q) { t1 += red1[q * DD + tid]; t2 += red2[q * DD + tid]; }
      float* ps = part + (size_t)l * (NB * 128) + b * 128;
      ps[tid]      = t1;
      ps[DD + tid] = t2;
    }

    stamp(arr, b, l + 1);        // partials visible, announce arrival
    wait_all(arr, l + 1);        // all 128 blocks' partials ready

    // ---- redundant distributed reduce (64 KB from L2, coalesced) ----
    if (tid < 128) {
      const float* pl = part + (size_t)l * (NB * 128) + tid;
      float s = 0.f;
#pragma unroll 8
      for (int j = 0; j < NB; ++j) s += pl[j * 128];
      red1[tid] = s;             // red1[0:64)=sums, red1[64:128)=sumsqs
    }
    __syncthreads();
    if (tid < DD) {
      float mu  = red1[tid] * (1.f / MT);
      float var = fmaxf(red1[DD + tid] * (1.f / MT) - mu * mu, 0.f);
      mus[tid] = mu;
      rss[tid] = rsqrtf(var + BN_EPS);
    }
    __syncthreads();

    // ---- normalize xsc in place; thread owns column d = tid>>2, quarter q ----
    {
      int d = tid >> 2, q = tid & 3;
      float mu = mus[d], rs = rss[d];
      float* p = xsc + d * XP + q * 16;
      float ps = 0.f;
#pragma unroll
      for (int w = 0; w < 4; ++w) {
        float4 v = *(const float4*)(p + w * 4);
        v.x = (v.x - mu) * rs; v.y = (v.y - mu) * rs;
        v.z = (v.z - mu) * rs; v.w = (v.w - mu) * rs;
        *(float4*)(p + w * 4) = v;
        ps += v.x + v.y + v.z + v.w;
      }
      poolp = ps;
    }
    if (l < 2) {
      for (int j = 0; j < 4; ++j) {
        int e = (tid + j * 256) * 4;
        int r = e >> 6, k = e & 63;
        float4 wv = *(const float4*)(Wf + (size_t)(l + 1) * 4096 + e);
        wT[(k + 0) * XP + r] = wv.x;
        wT[(k + 1) * XP + r] = wv.y;
        wT[(k + 2) * XP + r] = wv.z;
        wT[(k + 3) * XP + r] = wv.w;
      }
    } else {
      red1[tid] = poolp;   // pooling partials (wT region free on last layer)
    }
    __syncthreads();
  }

  // ---- pool: mean over the 64 nodes of this graph ----
  if (tid < DD) {
    float s = red1[tid * 4] + red1[tid * 4 + 1] + red1[tid * 4 + 2] + red1[tid * 4 + 3];
    mol[b * DD + tid] = s * (1.f / NPG);
  }

  stamp(arr, b, 4);        // arrival-only: blocks 1..127 retire immediately
  if (b != 0) return;
  wait_all(arr, 4);        // block 0 waits for all mol rows

  // ================= output MLP head, block 0 only =================
  float* t     = (float*)pool;                 // 128*TP floats = 34816 B
  float* wT2   = hs;                           // wT2[k*64+c] = Wo[c][k]
  float* hred1 = (float*)(pool + 51200);       // 4*64 floats
  float* hred2 = (float*)(pool + 52224);       // 4*64 floats

  const int lane = tid & 63;
  const int w4   = tid >> 6;            // 0..3

  for (int j = 0; j < 32; ++j) {
    int e = tid + j * 256;
    t[(e >> 6) * TP + (e & 63)] = mol[e];
  }

  float acc[32];
  for (int layer = 0; layer < 2; ++layer) {
    __syncthreads();
    for (int j = 0; j < 16; ++j) {
      int e = tid + j * 256;
      wT2[(e & 63) * 64 + (e >> 6)] = Wo[layer * 4096 + e];
    }
    float bias = bo[layer * 64 + lane];
    __syncthreads();
#pragma unroll
    for (int j = 0; j < 32; ++j) acc[j] = bias;
    for (int k = 0; k < 64; k += 4) {
      float wv0 = wT2[(k + 0) * 64 + lane];
      float wv1 = wT2[(k + 1) * 64 + lane];
      float wv2 = wT2[(k + 2) * 64 + lane];
      float wv3 = wT2[(k + 3) * 64 + lane];
#pragma unroll
      for (int j = 0; j < 32; ++j) {
        float4 tv = *(const float4*)(t + (w4 + 4 * j) * TP + k);  // broadcast
        acc[j] += tv.x * wv0 + tv.y * wv1 + tv.z * wv2 + tv.w * wv3;
      }
    }
    float s1 = 0.f, s2 = 0.f;
#pragma unroll
    for (int j = 0; j < 32; ++j) {
      acc[j] = selu_f(acc[j]);
      s1 += acc[j]; s2 += acc[j] * acc[j];
    }
    hred1[w4 * 64 + lane] = s1;
    hred2[w4 * 64 + lane] = s2;
    __syncthreads();
    if (tid < 64) {
      float a1 = 0.f, a2 = 0.f;
#pragma unroll
      for (int q = 0; q < 4; ++q) { a1 += hred1[q * 64 + tid]; a2 += hred2[q * 64 + tid]; }
      float mu  = a1 * (1.f / 128);
      float var = fmaxf(a2 * (1.f / 128) - mu * mu, 0.f);
      mus[tid] = mu;
      rss[tid] = rsqrtf(var + BN_EPS);
    }
    __syncthreads();
#pragma unroll
    for (int j = 0; j < 32; ++j)
      t[(w4 + 4 * j) * TP + lane] = (acc[j] - mus[lane]) * rss[lane];
  }
  __syncthreads();
  if (tid < 128) {
    float a = bp[0];
#pragma unroll 16
    for (int d = 0; d < 64; ++d) a += t[tid * TP + d] * Wp[d];
    out[tid] = a;
  }
}

extern "C" void kernel_launch(void* const* d_in, const int* in_sizes, int n_in,
                              void* d_out, int out_size, void* d_ws, size_t ws_size,
                              hipStream_t stream) {
  (void)in_sizes; (void)n_in; (void)out_size; (void)ws_size;
  const int*   fpr = (const int*)d_in[0];
  const float* adj = (const float*)d_in[1];
  const float* emb = (const float*)d_in[2];
  const float* Wf  = (const float*)d_in[3];
  const float* bfv = (const float*)d_in[4];
  const float* Wo  = (const float*)d_in[5];
  const float* bo  = (const float*)d_in[6];
  const float* Wp  = (const float*)d_in[7];
  const float* bp  = (const float*)d_in[8];

  float* ws   = (float*)d_ws;
  int*   arr  = (int*)ws;            // [128] arrival slots
  float* part = ws + 128;            // 3*128*128 floats BN partials
  float* mol  = ws + 128 + 49152;    // 8192 floats

  hipMemsetAsync(arr, 0, NB * sizeof(int), stream);   // guard first call only

  gnn_k<<<NB, 256, 0, stream>>>(fpr, emb, adj, Wf, bfv, Wo, bo, Wp, bp,
                                (float*)d_out, mol, part, arr);
}